// Round 1
// baseline (463.033 us; speedup 1.0000x reference)
//
#include <hip/hip_runtime.h>

// ---------------------------------------------------------------------------
// RNNModel: 3-layer tanh RNN (B=128, T=512, IN=768, H=64) + FC(64->1)
// K1: MFMA f16 GEMM, LDS-free: wave = 32x64 C-tile, frags loaded straight
//     from global (A rows are fragment-shaped), 8 mfma_16x16x32_f16 / K-chunk.
// K2: fused recurrence, 3 waves (wave=layer), EPOCHED: 8 steps per barrier.
//     Own-layer recurrence uses intra-wave LDS ordering (lgkmcnt), no barrier.
//     R1: g1/g2 epoch body restructured — rc reads issued first, input slots
//     double-buffered in registers, x-part dots on separate accumulators so
//     they fill the rc write->read latency window instead of extending the
//     recurrent dependency chain.
// ---------------------------------------------------------------------------

typedef __fp16 h2_t __attribute__((ext_vector_type(2)));
typedef __fp16 h8_t __attribute__((ext_vector_type(8)));
typedef float  f4_t __attribute__((ext_vector_type(4)));

union F4H { float4 f; h2_t h[4]; };
union H8U { h2_t h2[4]; h8_t h8; };

__device__ __forceinline__ float fdot2(h2_t a, h2_t b, float c) {
    return __builtin_amdgcn_fdot2(a, b, c, false);
}
__device__ __forceinline__ h2_t pack_h2(float x, float y) {
    return __builtin_amdgcn_cvt_pkrtz(x, y);
}
__device__ __forceinline__ float tanh_fast(float x) {
    float e = __expf(2.0f * x);
    return 1.0f - 2.0f * __builtin_amdgcn_rcpf(e + 1.0f);
}

// ---------------------------------------------------------------------------
// GEMM: grid 512 x 256thr. Wave w owns rows blk*128 + w*32 .. +32, cols 0..64.
// A frag: lane holds x[row = m][k = q*8 + j] (8 consecutive floats -> cvt).
// B frag: lane holds W[n = m][k = q*8 + j]  (Wih is [64][768] row-major).
// C/D: col = lane&15, row = (lane>>4)*4 + reg.
// ---------------------------------------------------------------------------
__global__ __launch_bounds__(256) void gemm_pre0(
    const float* __restrict__ x,    // [65536][768]
    const float* __restrict__ Wih,  // [64][768]
    const float* __restrict__ bih, const float* __restrict__ bhh,
    float* __restrict__ pre0)       // [65536][64]
{
    const int tid = threadIdx.x;
    const int wv  = tid >> 6;
    const int l   = tid & 63;
    const int m   = l & 15;          // row/col within 16-tile
    const int q   = l >> 4;          // k-quad
    const int rowB = blockIdx.x * 128 + wv * 32;

    const float* ax0 = x + (size_t)(rowB + m) * 768 + q * 8;
    const float* ax1 = x + (size_t)(rowB + 16 + m) * 768 + q * 8;

    float4 ar[2][2];
    float4 br[4][2];

    // prologue: chunk 0
    ar[0][0] = *(const float4*)ax0;       ar[0][1] = *(const float4*)(ax0 + 4);
    ar[1][0] = *(const float4*)ax1;       ar[1][1] = *(const float4*)(ax1 + 4);
#pragma unroll
    for (int nt = 0; nt < 4; ++nt) {
        const float* p = Wih + (size_t)(nt * 16 + m) * 768 + q * 8;
        br[nt][0] = *(const float4*)p;    br[nt][1] = *(const float4*)(p + 4);
    }

    f4_t acc[2][4];
#pragma unroll
    for (int mt = 0; mt < 2; ++mt)
#pragma unroll
        for (int nt = 0; nt < 4; ++nt)
#pragma unroll
            for (int i = 0; i < 4; ++i) acc[mt][nt][i] = 0.0f;

#pragma unroll
    for (int it = 0; it < 24; ++it) {
        // convert current raw -> frags
        H8U fa[2], fb[4];
#pragma unroll
        for (int mt = 0; mt < 2; ++mt) {
            fa[mt].h2[0] = pack_h2(ar[mt][0].x, ar[mt][0].y);
            fa[mt].h2[1] = pack_h2(ar[mt][0].z, ar[mt][0].w);
            fa[mt].h2[2] = pack_h2(ar[mt][1].x, ar[mt][1].y);
            fa[mt].h2[3] = pack_h2(ar[mt][1].z, ar[mt][1].w);
        }
#pragma unroll
        for (int nt = 0; nt < 4; ++nt) {
            fb[nt].h2[0] = pack_h2(br[nt][0].x, br[nt][0].y);
            fb[nt].h2[1] = pack_h2(br[nt][0].z, br[nt][0].w);
            fb[nt].h2[2] = pack_h2(br[nt][1].x, br[nt][1].y);
            fb[nt].h2[3] = pack_h2(br[nt][1].z, br[nt][1].w);
        }
        // issue next chunk's loads (reg reads happen at cvt issue; safe WAR)
        if (it + 1 < 24) {
            const int ko = (it + 1) * 32;
            ar[0][0] = *(const float4*)(ax0 + ko);
            ar[0][1] = *(const float4*)(ax0 + ko + 4);
            ar[1][0] = *(const float4*)(ax1 + ko);
            ar[1][1] = *(const float4*)(ax1 + ko + 4);
#pragma unroll
            for (int nt = 0; nt < 4; ++nt) {
                const float* p = Wih + (size_t)(nt * 16 + m) * 768 + q * 8 + ko;
                br[nt][0] = *(const float4*)p;
                br[nt][1] = *(const float4*)(p + 4);
            }
        }
#pragma unroll
        for (int mt = 0; mt < 2; ++mt)
#pragma unroll
            for (int nt = 0; nt < 4; ++nt)
                acc[mt][nt] = __builtin_amdgcn_mfma_f32_16x16x32_f16(
                    fa[mt].h8, fb[nt].h8, acc[mt][nt], 0, 0, 0);
    }

    // epilogue: bias + store (col = nt*16 + m, row = rowB + mt*16 + q*4 + i)
    float bn[4];
#pragma unroll
    for (int nt = 0; nt < 4; ++nt) bn[nt] = bih[nt * 16 + m] + bhh[nt * 16 + m];
#pragma unroll
    for (int mt = 0; mt < 2; ++mt)
#pragma unroll
        for (int i = 0; i < 4; ++i) {
            int row = rowB + mt * 16 + q * 4 + i;
            float* pr = pre0 + (size_t)row * 64 + m;
#pragma unroll
            for (int nt = 0; nt < 4; ++nt)
                pr[nt * 16] = acc[mt][nt][i] + bn[nt];
        }
}

// ---------------------------------------------------------------------------
// One epoch (8 steps) of a middle/top layer wave.
//   in0    : base of the 8 input slots (lower layer, previous epoch, synced)
//   self0  : base of own layer's hb[2][8][64] (parity-0 slot 0)
//   par    : parity this epoch writes
// Per step: (1) issue own-recurrence reads first (longest latency),
//           (2) prefetch next input slot into the alternate register buffer,
//           (3) x-part dots on separate accumulators fill the rc wait,
//           (4) recurrent dots + tanh + LDS write.
// ---------------------------------------------------------------------------
__device__ __forceinline__ float layer_epoch(
    const __fp16* __restrict__ in0,
    __fp16* __restrict__ self0, int par,
    const h2_t* wA2, const h2_t* wB2, float bias, int j)
{
    __fp16*       selfPar  = self0 + par * 512;         // 8*64
    const __fp16* selfPrev = self0 + (par ^ 1) * 512;

    F4H u0[8], u1[8];
#pragma unroll
    for (int qq = 0; qq < 8; ++qq) u0[qq].f = *(const float4*)(in0 + qq * 8);

    float hN = 0.0f;
#pragma unroll
    for (int s = 0; s < 8; ++s) {
        const F4H* uc = (s & 1) ? u1 : u0;
        F4H*       un = (s & 1) ? u0 : u1;

        // (1) own-recurrence reads: issue first, latency starts now
        const __fp16* rc = (s == 0) ? (selfPrev + 7 * 64) : (selfPar + (s - 1) * 64);
        F4H uh[8];
#pragma unroll
        for (int qq = 0; qq < 8; ++qq) uh[qq].f = *(const float4*)(rc + qq * 8);

        // (2) prefetch next step's input slot (independent, previous epoch data)
        if (s < 7) {
#pragma unroll
            for (int qq = 0; qq < 8; ++qq)
                un[qq].f = *(const float4*)(in0 + (s + 1) * 64 + qq * 8);
        }

        // (3) x-part dots from already-resident registers — separate accums,
        //     executes inside the rc read-latency window
        float x0 = 0.f, x1 = 0.f, x2 = 0.f, x3 = 0.f;
#pragma unroll
        for (int qq = 0; qq < 8; ++qq) {
            x0 = fdot2(wA2[qq * 4 + 0], uc[qq].h[0], x0);
            x1 = fdot2(wA2[qq * 4 + 1], uc[qq].h[1], x1);
            x2 = fdot2(wA2[qq * 4 + 2], uc[qq].h[2], x2);
            x3 = fdot2(wA2[qq * 4 + 3], uc[qq].h[3], x3);
        }
        float xs = (x0 + x1) + (x2 + x3) + bias;

        // (4) recurrent dots — the true sequential chain (32 fdot2 only)
        float a0 = 0.f, a1 = 0.f, a2 = 0.f, a3 = 0.f;
#pragma unroll
        for (int qq = 0; qq < 8; ++qq) {
            a0 = fdot2(wB2[qq * 4 + 0], uh[qq].h[0], a0);
            a1 = fdot2(wB2[qq * 4 + 1], uh[qq].h[1], a1);
            a2 = fdot2(wB2[qq * 4 + 2], uh[qq].h[2], a2);
            a3 = fdot2(wB2[qq * 4 + 3], uh[qq].h[3], a3);
        }
        hN = tanh_fast((a0 + a1) + (a2 + a3) + xs);
        selfPar[s * 64 + j] = (__fp16)hN;
    }
    return hN;   // h of last step of this epoch
}

// ---------------------------------------------------------------------------
// Recurrence: block = batch element, 3 waves (wave g = layer g).
// Epochs of S=8 steps; ONE barrier per epoch. hb[layer][parity][slot][unit]:
// wave g writes slots of epoch e with parity e_g&1; consumer reads them
// next epoch (opposite parity) — WAR separated by exactly one barrier.
// ---------------------------------------------------------------------------
__global__ __launch_bounds__(192, 1) void rnn_fused(
    const float* __restrict__ pre0,  // [128*512][64], layer-0 biases folded in
    const float* __restrict__ Whh0,
    const float* __restrict__ Wih1, const float* __restrict__ Whh1,
    const float* __restrict__ bih1, const float* __restrict__ bhh1,
    const float* __restrict__ Wih2, const float* __restrict__ Whh2,
    const float* __restrict__ bih2, const float* __restrict__ bhh2,
    const float* __restrict__ fcw, const float* __restrict__ fcb,
    float* __restrict__ out)
{
    const int tid = threadIdx.x;
    const int g   = tid >> 6;        // layer 0..2
    const int j   = tid & 63;        // output unit
    const int b   = blockIdx.x;

    __shared__ __align__(16) __fp16 hb[3][2][8][64];

    // packed f16 weight rows in VGPRs
    const float* WA = (g == 0) ? Whh0 : ((g == 1) ? Wih1 : Wih2);
    const float* WB = (g == 0) ? Whh0 : ((g == 1) ? Whh1 : Whh2);  // g0: dummy
    h2_t wA2[32], wB2[32];
#pragma unroll
    for (int i = 0; i < 32; ++i) {
        wA2[i] = pack_h2(WA[j * 64 + 2 * i], WA[j * 64 + 2 * i + 1]);
        wB2[i] = pack_h2(WB[j * 64 + 2 * i], WB[j * 64 + 2 * i + 1]);
    }
    const float bias = (g == 0) ? 0.0f
                     : ((g == 1) ? (bih1[j] + bhh1[j]) : (bih2[j] + bhh2[j]));

    // zero all of hb: 3*2*8*64 f16 = 1536 dwords / 192 thr = 8 each
#pragma unroll
    for (int i = 0; i < 8; ++i) ((unsigned int*)hb)[tid + 192 * i] = 0u;

    // pre0 double-buffered epoch prefetch (wave 0)
    const size_t pbase = (size_t)b * 32768;
    float pc[8], pn[8];
    if (g == 0) {
#pragma unroll
        for (int s = 0; s < 8; ++s) pc[s] = pre0[pbase + s * 64 + j];
    }
    __syncthreads();

    float hLast = 0.0f;

    for (int e = 0; e < 66; ++e) {
        if (g == 0) {
            if (e < 64) {
                if (e < 63) {
#pragma unroll
                    for (int s = 0; s < 8; ++s)
                        pn[s] = pre0[pbase + (size_t)(e + 1) * 512 + s * 64 + j];
                }
                const int par = e & 1;
#pragma unroll
                for (int s = 0; s < 8; ++s) {
                    const __fp16* rc = (s == 0) ? hb[0][par ^ 1][7] : hb[0][par][s - 1];
                    float a0 = 0.f, a1 = 0.f, a2 = 0.f, a3 = 0.f;
#pragma unroll
                    for (int qq = 0; qq < 8; ++qq) {
                        F4H u; u.f = *(const float4*)&rc[qq * 8];
                        a0 = fdot2(wA2[qq * 4 + 0], u.h[0], a0);
                        a1 = fdot2(wA2[qq * 4 + 1], u.h[1], a1);
                        a2 = fdot2(wA2[qq * 4 + 2], u.h[2], a2);
                        a3 = fdot2(wA2[qq * 4 + 3], u.h[3], a3);
                    }
                    float hN = tanh_fast((a0 + a1) + (a2 + a3) + pc[s]);
                    hb[0][par][s][j] = (__fp16)hN;
                }
#pragma unroll
                for (int s = 0; s < 8; ++s) pc[s] = pn[s];
            }
        } else if (g == 1) {
            if (e >= 1 && e < 65) {
                const int par = (e - 1) & 1;
                layer_epoch(&hb[0][par][0][0], &hb[1][0][0][0], par,
                            wA2, wB2, bias, j);
            }
        } else {
            if (e >= 2) {
                const int par = e & 1;   // == (e-2)&1
                float hN = layer_epoch(&hb[1][par][0][0], &hb[2][0][0][0], par,
                                       wA2, wB2, bias, j);
                if (e == 65) hLast = hN;   // t = 511
            }
        }
        __syncthreads();
    }

    // FC epilogue on wave 2
    if (g == 2) {
        float v = hLast * fcw[j];
#pragma unroll
        for (int m = 1; m < 64; m <<= 1) v += __shfl_xor(v, m, 64);
        if (j == 0) out[b] = v + fcb[0];
    }
}

extern "C" void kernel_launch(void* const* d_in, const int* in_sizes, int n_in,
                              void* d_out, int out_size, void* d_ws, size_t ws_size,
                              hipStream_t stream) {
    const float* x    = (const float*)d_in[0];
    const float* Wih0 = (const float*)d_in[2];
    const float* Whh0 = (const float*)d_in[3];
    const float* bih0 = (const float*)d_in[4];
    const float* bhh0 = (const float*)d_in[5];
    const float* Wih1 = (const float*)d_in[6];
    const float* Whh1 = (const float*)d_in[7];
    const float* bih1 = (const float*)d_in[8];
    const float* bhh1 = (const float*)d_in[9];
    const float* Wih2 = (const float*)d_in[10];
    const float* Whh2 = (const float*)d_in[11];
    const float* bih2 = (const float*)d_in[12];
    const float* bhh2 = (const float*)d_in[13];
    const float* fcw  = (const float*)d_in[14];
    const float* fcb  = (const float*)d_in[15];
    float* out  = (float*)d_out;
    float* pre0 = (float*)d_ws;   // 16.78 MB fp32

    gemm_pre0<<<512, 256, 0, stream>>>(x, Wih0, bih0, bhh0, pre0);
    rnn_fused<<<128, 192, 0, stream>>>(pre0, Whh0, Wih1, Whh1, bih1, bhh1,
                                       Wih2, Whh2, bih2, bhh2, fcw, fcb, out);
}

// Round 2
// 430.467 us; speedup vs baseline: 1.0757x; 1.0757x over previous
//
#include <hip/hip_runtime.h>

// ---------------------------------------------------------------------------
// RNNModel: 3-layer tanh RNN (B=128, T=512, IN=768, H=64) + FC(64->1)
// K1: MFMA f16 GEMM, LDS-free: wave = 32x64 C-tile, frags loaded straight
//     from global (A rows are fragment-shaped), 8 mfma_16x16x32_f16 / K-chunk.
// K2: fused recurrence, 3 waves (wave=layer), EPOCHED: 8 steps per barrier.
//     R2: x-part (W_ih . h_lower) for layers 1/2 computed ONCE PER EPOCH via
//     MFMA (8x64 @ 64x64 over the epoch's 8 slots) into a small LDS xb buffer;
//     per-step work is only the recurrent 32 fdot2 + tanh. This removes the
//     16 broadcast ds_read_b128/step of the x-part (LDS-BW was the bottleneck:
//     40 wave-wide b128 broadcasts/step ~ 320cy of the shared LDS pipe).
// ---------------------------------------------------------------------------

typedef __fp16 h2_t __attribute__((ext_vector_type(2)));
typedef __fp16 h8_t __attribute__((ext_vector_type(8)));
typedef float  f4_t __attribute__((ext_vector_type(4)));

union F4H  { float4 f; h2_t h[4]; };
union F4H8 { float4 f; h8_t h8; h2_t h2[4]; };
union H8U  { h2_t h2[4]; h8_t h8; };

__device__ __forceinline__ float fdot2(h2_t a, h2_t b, float c) {
    return __builtin_amdgcn_fdot2(a, b, c, false);
}
__device__ __forceinline__ h2_t pack_h2(float x, float y) {
    return __builtin_amdgcn_cvt_pkrtz(x, y);
}
__device__ __forceinline__ float tanh_fast(float x) {
    float e = __expf(2.0f * x);
    return 1.0f - 2.0f * __builtin_amdgcn_rcpf(e + 1.0f);
}

// ---------------------------------------------------------------------------
// GEMM: grid 512 x 256thr. Wave w owns rows blk*128 + w*32 .. +32, cols 0..64.
// A frag: lane holds x[row = m][k = q*8 + j] (8 consecutive floats -> cvt).
// B frag: lane holds W[n = m][k = q*8 + j]  (Wih is [64][768] row-major).
// C/D: col = lane&15, row = (lane>>4)*4 + reg.
// ---------------------------------------------------------------------------
__global__ __launch_bounds__(256) void gemm_pre0(
    const float* __restrict__ x,    // [65536][768]
    const float* __restrict__ Wih,  // [64][768]
    const float* __restrict__ bih, const float* __restrict__ bhh,
    float* __restrict__ pre0)       // [65536][64]
{
    const int tid = threadIdx.x;
    const int wv  = tid >> 6;
    const int l   = tid & 63;
    const int m   = l & 15;          // row/col within 16-tile
    const int q   = l >> 4;          // k-quad
    const int rowB = blockIdx.x * 128 + wv * 32;

    const float* ax0 = x + (size_t)(rowB + m) * 768 + q * 8;
    const float* ax1 = x + (size_t)(rowB + 16 + m) * 768 + q * 8;

    float4 ar[2][2];
    float4 br[4][2];

    // prologue: chunk 0
    ar[0][0] = *(const float4*)ax0;       ar[0][1] = *(const float4*)(ax0 + 4);
    ar[1][0] = *(const float4*)ax1;       ar[1][1] = *(const float4*)(ax1 + 4);
#pragma unroll
    for (int nt = 0; nt < 4; ++nt) {
        const float* p = Wih + (size_t)(nt * 16 + m) * 768 + q * 8;
        br[nt][0] = *(const float4*)p;    br[nt][1] = *(const float4*)(p + 4);
    }

    f4_t acc[2][4];
#pragma unroll
    for (int mt = 0; mt < 2; ++mt)
#pragma unroll
        for (int nt = 0; nt < 4; ++nt)
#pragma unroll
            for (int i = 0; i < 4; ++i) acc[mt][nt][i] = 0.0f;

#pragma unroll
    for (int it = 0; it < 24; ++it) {
        // convert current raw -> frags
        H8U fa[2], fb[4];
#pragma unroll
        for (int mt = 0; mt < 2; ++mt) {
            fa[mt].h2[0] = pack_h2(ar[mt][0].x, ar[mt][0].y);
            fa[mt].h2[1] = pack_h2(ar[mt][0].z, ar[mt][0].w);
            fa[mt].h2[2] = pack_h2(ar[mt][1].x, ar[mt][1].y);
            fa[mt].h2[3] = pack_h2(ar[mt][1].z, ar[mt][1].w);
        }
#pragma unroll
        for (int nt = 0; nt < 4; ++nt) {
            fb[nt].h2[0] = pack_h2(br[nt][0].x, br[nt][0].y);
            fb[nt].h2[1] = pack_h2(br[nt][0].z, br[nt][0].w);
            fb[nt].h2[2] = pack_h2(br[nt][1].x, br[nt][1].y);
            fb[nt].h2[3] = pack_h2(br[nt][1].z, br[nt][1].w);
        }
        // issue next chunk's loads (reg reads happen at cvt issue; safe WAR)
        if (it + 1 < 24) {
            const int ko = (it + 1) * 32;
            ar[0][0] = *(const float4*)(ax0 + ko);
            ar[0][1] = *(const float4*)(ax0 + ko + 4);
            ar[1][0] = *(const float4*)(ax1 + ko);
            ar[1][1] = *(const float4*)(ax1 + ko + 4);
#pragma unroll
            for (int nt = 0; nt < 4; ++nt) {
                const float* p = Wih + (size_t)(nt * 16 + m) * 768 + q * 8 + ko;
                br[nt][0] = *(const float4*)p;
                br[nt][1] = *(const float4*)(p + 4);
            }
        }
#pragma unroll
        for (int mt = 0; mt < 2; ++mt)
#pragma unroll
            for (int nt = 0; nt < 4; ++nt)
                acc[mt][nt] = __builtin_amdgcn_mfma_f32_16x16x32_f16(
                    fa[mt].h8, fb[nt].h8, acc[mt][nt], 0, 0, 0);
    }

    // epilogue: bias + store (col = nt*16 + m, row = rowB + mt*16 + q*4 + i)
    float bn[4];
#pragma unroll
    for (int nt = 0; nt < 4; ++nt) bn[nt] = bih[nt * 16 + m] + bhh[nt * 16 + m];
#pragma unroll
    for (int mt = 0; mt < 2; ++mt)
#pragma unroll
        for (int i = 0; i < 4; ++i) {
            int row = rowB + mt * 16 + q * 4 + i;
            float* pr = pre0 + (size_t)row * 64 + m;
#pragma unroll
            for (int nt = 0; nt < 4; ++nt)
                pr[nt * 16] = acc[mt][nt][i] + bn[nt];
        }
}

// ---------------------------------------------------------------------------
// One epoch (8 steps) of a middle/top layer wave.
// Prologue: x-part for ALL 8 slots via MFMA. A = Hlower[16(8 real)][64] read
// as 2 ds_read_b128/lane; B = Wih^T pre-packed frags (wX). D layout (same as
// K1, verified): col(unit)=lane&15, row(slot)=(lane>>4)*4+i -> real slots live
// in lanes 0..31; scatter f32 to xb[slot][unit].
// Steps: 8 broadcast b128 (own recurrence) + 1 b32 (xs) + 32 fdot2 + tanh.
// ---------------------------------------------------------------------------
__device__ __forceinline__ float layer_epoch(
    const __fp16* __restrict__ in0,
    __fp16* __restrict__ self0, int par,
    const h2_t* wB2, const h8_t* wX, float* __restrict__ xb,
    float bias, int j)
{
    __fp16*       selfPar  = self0 + par * 512;         // 8*64
    const __fp16* selfPrev = self0 + (par ^ 1) * 512;
    const int mm = j & 15;
    const int q4 = j >> 4;

    // ---- x-part MFMA prologue (slots 8..15 of A are garbage rows; their
    //      outputs land in lanes >=32 and are never scattered) ----
    F4H8 A0, A1;
    const __fp16* arow = in0 + mm * 64 + q4 * 8;
    A0.f = *(const float4*)arow;
    A1.f = *(const float4*)(arow + 32);

    f4_t xacc[4];
#pragma unroll
    for (int nt = 0; nt < 4; ++nt) {
#pragma unroll
        for (int i = 0; i < 4; ++i) xacc[nt][i] = 0.0f;
        xacc[nt] = __builtin_amdgcn_mfma_f32_16x16x32_f16(
            A0.h8, wX[nt * 2 + 0], xacc[nt], 0, 0, 0);
        xacc[nt] = __builtin_amdgcn_mfma_f32_16x16x32_f16(
            A1.h8, wX[nt * 2 + 1], xacc[nt], 0, 0, 0);
    }
    if (j < 32) {                    // q4 in {0,1} -> slots 0..7
#pragma unroll
        for (int nt = 0; nt < 4; ++nt)
#pragma unroll
            for (int i = 0; i < 4; ++i)
                xb[(q4 * 4 + i) * 64 + nt * 16 + mm] = xacc[nt][i];
    }

    // ---- 8 recurrent steps ----
    float hN = 0.0f;
#pragma unroll
    for (int s = 0; s < 8; ++s) {
        const __fp16* rc = (s == 0) ? (selfPrev + 7 * 64) : (selfPar + (s - 1) * 64);
        F4H uh[8];
#pragma unroll
        for (int qq = 0; qq < 8; ++qq) uh[qq].f = *(const float4*)(rc + qq * 8);
        float xs = xb[s * 64 + j];

        float a0 = 0.f, a1 = 0.f, a2 = 0.f, a3 = 0.f;
#pragma unroll
        for (int qq = 0; qq < 8; ++qq) {
            a0 = fdot2(wB2[qq * 4 + 0], uh[qq].h[0], a0);
            a1 = fdot2(wB2[qq * 4 + 1], uh[qq].h[1], a1);
            a2 = fdot2(wB2[qq * 4 + 2], uh[qq].h[2], a2);
            a3 = fdot2(wB2[qq * 4 + 3], uh[qq].h[3], a3);
        }
        hN = tanh_fast((a0 + a1) + (a2 + a3) + xs + bias);
        selfPar[s * 64 + j] = (__fp16)hN;
    }
    return hN;   // h of last step of this epoch
}

// ---------------------------------------------------------------------------
// Recurrence: block = batch element, 3 waves (wave g = layer g).
// Epochs of S=8 steps; ONE barrier per epoch. hb[layer][parity][slot][unit]:
// wave g writes slots of epoch e with parity e_g&1; consumer reads them
// next epoch (opposite parity) — WAR separated by exactly one barrier.
// xb2[g-1] is written+read by the SAME wave within an epoch (lgkm ordering).
// ---------------------------------------------------------------------------
__global__ __launch_bounds__(192, 1) void rnn_fused(
    const float* __restrict__ pre0,  // [128*512][64], layer-0 biases folded in
    const float* __restrict__ Whh0,
    const float* __restrict__ Wih1, const float* __restrict__ Whh1,
    const float* __restrict__ bih1, const float* __restrict__ bhh1,
    const float* __restrict__ Wih2, const float* __restrict__ Whh2,
    const float* __restrict__ bih2, const float* __restrict__ bhh2,
    const float* __restrict__ fcw, const float* __restrict__ fcb,
    float* __restrict__ out)
{
    const int tid = threadIdx.x;
    const int g   = tid >> 6;        // layer 0..2
    const int j   = tid & 63;        // output unit
    const int b   = blockIdx.x;

    __shared__ __align__(16) __fp16 hb[3][2][8][64];
    __shared__ __align__(16) float  xb2[2][8][64];

    // recurrent (Whh) rows packed f16, fdot2 path — all waves
    const float* WB = (g == 0) ? Whh0 : ((g == 1) ? Whh1 : Whh2);
    h2_t wB2[32];
#pragma unroll
    for (int i = 0; i < 32; ++i)
        wB2[i] = pack_h2(WB[j * 64 + 2 * i], WB[j * 64 + 2 * i + 1]);

    // Wih B-frags for the per-epoch x-MFMA (g1/g2; g0 loads dummy from Whh0)
    const float* WX = (g == 1) ? Wih1 : ((g == 2) ? Wih2 : Whh0);
    const int mm = j & 15, q4 = j >> 4;
    h8_t wX[8];
#pragma unroll
    for (int nt = 0; nt < 4; ++nt)
#pragma unroll
        for (int c = 0; c < 2; ++c) {
            const float* p = WX + (nt * 16 + mm) * 64 + c * 32 + q4 * 8;
            float4 r0 = *(const float4*)p;
            float4 r1 = *(const float4*)(p + 4);
            H8U u;
            u.h2[0] = pack_h2(r0.x, r0.y); u.h2[1] = pack_h2(r0.z, r0.w);
            u.h2[2] = pack_h2(r1.x, r1.y); u.h2[3] = pack_h2(r1.z, r1.w);
            wX[nt * 2 + c] = u.h8;
        }

    const float bias = (g == 0) ? 0.0f
                     : ((g == 1) ? (bih1[j] + bhh1[j]) : (bih2[j] + bhh2[j]));

    // zero all of hb: 3*2*8*64 f16 = 1536 dwords / 192 thr = 8 each
#pragma unroll
    for (int i = 0; i < 8; ++i) ((unsigned int*)hb)[tid + 192 * i] = 0u;

    // pre0 double-buffered epoch prefetch (wave 0)
    const size_t pbase = (size_t)b * 32768;
    float pc[8], pn[8];
    if (g == 0) {
#pragma unroll
        for (int s = 0; s < 8; ++s) pc[s] = pre0[pbase + s * 64 + j];
    }
    __syncthreads();

    float hLast = 0.0f;

    for (int e = 0; e < 66; ++e) {
        if (g == 0) {
            if (e < 64) {
                if (e < 63) {
#pragma unroll
                    for (int s = 0; s < 8; ++s)
                        pn[s] = pre0[pbase + (size_t)(e + 1) * 512 + s * 64 + j];
                }
                const int par = e & 1;
#pragma unroll
                for (int s = 0; s < 8; ++s) {
                    const __fp16* rc = (s == 0) ? hb[0][par ^ 1][7] : hb[0][par][s - 1];
                    float a0 = 0.f, a1 = 0.f, a2 = 0.f, a3 = 0.f;
#pragma unroll
                    for (int qq = 0; qq < 8; ++qq) {
                        F4H u; u.f = *(const float4*)&rc[qq * 8];
                        a0 = fdot2(wB2[qq * 4 + 0], u.h[0], a0);
                        a1 = fdot2(wB2[qq * 4 + 1], u.h[1], a1);
                        a2 = fdot2(wB2[qq * 4 + 2], u.h[2], a2);
                        a3 = fdot2(wB2[qq * 4 + 3], u.h[3], a3);
                    }
                    float hN = tanh_fast((a0 + a1) + (a2 + a3) + pc[s]);
                    hb[0][par][s][j] = (__fp16)hN;
                }
#pragma unroll
                for (int s = 0; s < 8; ++s) pc[s] = pn[s];
            }
        } else if (g == 1) {
            if (e >= 1 && e < 65) {
                const int par = (e - 1) & 1;
                layer_epoch(&hb[0][par][0][0], &hb[1][0][0][0], par,
                            wB2, wX, &xb2[0][0][0], bias, j);
            }
        } else {
            if (e >= 2) {
                const int par = e & 1;   // == (e-2)&1
                float hN = layer_epoch(&hb[1][par][0][0], &hb[2][0][0][0], par,
                                       wB2, wX, &xb2[1][0][0], bias, j);
                if (e == 65) hLast = hN;   // t = 511
            }
        }
        __syncthreads();
    }

    // FC epilogue on wave 2
    if (g == 2) {
        float v = hLast * fcw[j];
#pragma unroll
        for (int m = 1; m < 64; m <<= 1) v += __shfl_xor(v, m, 64);
        if (j == 0) out[b] = v + fcb[0];
    }
}

extern "C" void kernel_launch(void* const* d_in, const int* in_sizes, int n_in,
                              void* d_out, int out_size, void* d_ws, size_t ws_size,
                              hipStream_t stream) {
    const float* x    = (const float*)d_in[0];
    const float* Wih0 = (const float*)d_in[2];
    const float* Whh0 = (const float*)d_in[3];
    const float* bih0 = (const float*)d_in[4];
    const float* bhh0 = (const float*)d_in[5];
    const float* Wih1 = (const float*)d_in[6];
    const float* Whh1 = (const float*)d_in[7];
    const float* bih1 = (const float*)d_in[8];
    const float* bhh1 = (const float*)d_in[9];
    const float* Wih2 = (const float*)d_in[10];
    const float* Whh2 = (const float*)d_in[11];
    const float* bih2 = (const float*)d_in[12];
    const float* bhh2 = (const float*)d_in[13];
    const float* fcw  = (const float*)d_in[14];
    const float* fcb  = (const float*)d_in[15];
    float* out  = (float*)d_out;
    float* pre0 = (float*)d_ws;   // 16.78 MB fp32

    gemm_pre0<<<512, 256, 0, stream>>>(x, Wih0, bih0, bhh0, pre0);
    rnn_fused<<<128, 192, 0, stream>>>(pre0, Whh0, Wih1, Whh1, bih1, bhh1,
                                       Wih2, Whh2, bih2, bhh2, fcw, fcb, out);
}

// Round 3
// 414.403 us; speedup vs baseline: 1.1174x; 1.0388x over previous
//
#include <hip/hip_runtime.h>

// ---------------------------------------------------------------------------
// RNNModel: 3-layer tanh RNN (B=128, T=512, IN=768, H=64) + FC(64->1)
// K0: pack_wih — one-shot Wih f32 -> fragment-ordered f16 (96 KB in ws).
// K1: MFMA f16 GEMM, LDS-free: wave = 16x64 C-tile (4096 waves, 4/SIMD),
//     A frags direct from global (depth-2 prefetch), B frags preconverted
//     (coalesced h8 loads, zero cvt).  R3.
// K2: fused recurrence, 3 waves (wave=layer), EPOCHED: 16 steps per barrier.
//     x-part (W_ih . h_lower) once per epoch via MFMA (full 16x64, no waste),
//     biases folded into the xb scatter, xs read back into registers once per
//     epoch (same-wave LDS ordering). Per-step chain: 8 b128 rc reads ->
//     32 fdot2 -> tanh -> b16 write.  R3.
// ---------------------------------------------------------------------------

typedef __fp16 h2_t __attribute__((ext_vector_type(2)));
typedef __fp16 h8_t __attribute__((ext_vector_type(8)));
typedef float  f4_t __attribute__((ext_vector_type(4)));

union F4H  { float4 f; h2_t h[4]; };
union F4H8 { float4 f; h8_t h8; h2_t h2[4]; };
union H8U  { h2_t h2[4]; h8_t h8; };

__device__ __forceinline__ float fdot2(h2_t a, h2_t b, float c) {
    return __builtin_amdgcn_fdot2(a, b, c, false);
}
__device__ __forceinline__ h2_t pack_h2(float x, float y) {
    return __builtin_amdgcn_cvt_pkrtz(x, y);
}
__device__ __forceinline__ float tanh_fast(float x) {
    float e = __expf(2.0f * x);
    return 1.0f - 2.0f * __builtin_amdgcn_rcpf(e + 1.0f);
}

// ---------------------------------------------------------------------------
// K0: Wih [64][768] f32 -> wp[chunk][nt][lane] = 8 f16 (frag element order:
// lane l holds W[nt*16 + (l&15)][chunk*32 + (l>>4)*8 + t], t=0..7).
// 24 chunks * 4 nt * 64 lanes = 6144 frags.
// ---------------------------------------------------------------------------
__global__ __launch_bounds__(256) void pack_wih(
    const float* __restrict__ W, h8_t* __restrict__ wp)
{
    const int id = blockIdx.x * 256 + threadIdx.x;
    if (id >= 24 * 4 * 64) return;
    const int l  = id & 63;
    const int nt = (id >> 6) & 3;
    const int c  = id >> 8;
    const float* p = W + (size_t)(nt * 16 + (l & 15)) * 768 + c * 32 + (l >> 4) * 8;
    float4 r0 = *(const float4*)p;
    float4 r1 = *(const float4*)(p + 4);
    H8U u;
    u.h2[0] = pack_h2(r0.x, r0.y); u.h2[1] = pack_h2(r0.z, r0.w);
    u.h2[2] = pack_h2(r1.x, r1.y); u.h2[3] = pack_h2(r1.z, r1.w);
    wp[id] = u.h8;
}

// ---------------------------------------------------------------------------
// K1: grid 1024 x 256thr. Wave w owns rows blk*64 + w*16, cols 0..64.
// A frag: lane holds x[row = m][k = q*8 + t] (2 float4 -> cvt).
// B frag: preconverted h8 load (coalesced).
// C/D: col = lane&15, row = (lane>>4)*4 + reg.
// Depth-2 software pipeline on both A and B.
// ---------------------------------------------------------------------------
__global__ __launch_bounds__(256) void gemm_pre0(
    const float* __restrict__ x,    // [65536][768]
    const h8_t* __restrict__ wp,    // packed Wih frags
    const float* __restrict__ bih, const float* __restrict__ bhh,
    float* __restrict__ pre0)       // [65536][64]
{
    const int tid = threadIdx.x;
    const int wv  = tid >> 6;
    const int l   = tid & 63;
    const int m   = l & 15;          // row within 16-tile / col within n-tile
    const int q   = l >> 4;          // k-quad
    const int rowB = blockIdx.x * 64 + wv * 16;

    const float* ax = x + (size_t)(rowB + m) * 768 + q * 8;

    float4 ar[2][2];
    h8_t   bf[2][4];

    // preload chunks 0 and 1
#pragma unroll
    for (int c = 0; c < 2; ++c) {
        ar[c][0] = *(const float4*)(ax + c * 32);
        ar[c][1] = *(const float4*)(ax + c * 32 + 4);
        const int cb = c * 256 + l;
        bf[c][0] = wp[cb];        bf[c][1] = wp[cb + 64];
        bf[c][2] = wp[cb + 128];  bf[c][3] = wp[cb + 192];
    }

    f4_t acc[4];
#pragma unroll
    for (int nt = 0; nt < 4; ++nt)
#pragma unroll
        for (int i = 0; i < 4; ++i) acc[nt][i] = 0.0f;

#pragma unroll
    for (int it = 0; it < 24; ++it) {
        const int bs = it & 1;
        // consume current slot into locals (before prefetch overwrites)
        H8U fa;
        fa.h2[0] = pack_h2(ar[bs][0].x, ar[bs][0].y);
        fa.h2[1] = pack_h2(ar[bs][0].z, ar[bs][0].w);
        fa.h2[2] = pack_h2(ar[bs][1].x, ar[bs][1].y);
        fa.h2[3] = pack_h2(ar[bs][1].z, ar[bs][1].w);
        h8_t fb0 = bf[bs][0], fb1 = bf[bs][1], fb2 = bf[bs][2], fb3 = bf[bs][3];

        // prefetch chunk it+2 into this slot
        if (it + 2 < 24) {
            const int ko = (it + 2) * 32;
            ar[bs][0] = *(const float4*)(ax + ko);
            ar[bs][1] = *(const float4*)(ax + ko + 4);
            const int cb = (it + 2) * 256 + l;
            bf[bs][0] = wp[cb];        bf[bs][1] = wp[cb + 64];
            bf[bs][2] = wp[cb + 128];  bf[bs][3] = wp[cb + 192];
        }

        acc[0] = __builtin_amdgcn_mfma_f32_16x16x32_f16(fa.h8, fb0, acc[0], 0, 0, 0);
        acc[1] = __builtin_amdgcn_mfma_f32_16x16x32_f16(fa.h8, fb1, acc[1], 0, 0, 0);
        acc[2] = __builtin_amdgcn_mfma_f32_16x16x32_f16(fa.h8, fb2, acc[2], 0, 0, 0);
        acc[3] = __builtin_amdgcn_mfma_f32_16x16x32_f16(fa.h8, fb3, acc[3], 0, 0, 0);
    }

    // epilogue: bias + store (col = nt*16 + m, row = rowB + q*4 + i)
    float bn[4];
#pragma unroll
    for (int nt = 0; nt < 4; ++nt) bn[nt] = bih[nt * 16 + m] + bhh[nt * 16 + m];
#pragma unroll
    for (int i = 0; i < 4; ++i) {
        int row = rowB + q * 4 + i;
        float* pr = pre0 + (size_t)row * 64 + m;
#pragma unroll
        for (int nt = 0; nt < 4; ++nt)
            pr[nt * 16] = acc[nt][i] + bn[nt];
    }
}

// ---------------------------------------------------------------------------
// One epoch (16 steps) of a middle/top layer wave.
// Prologue: x-part for all 16 slots via MFMA (A = Hlower[16][64], 2 b128/lane;
// B = Wih pre-packed frags). D layout: col(unit)=lane&15, row(slot)=
// (lane>>4)*4+i -> all 64 lanes scatter. Biases folded into xb. Then read
// back this lane's 16 xs values into registers (same-wave LDS ordering).
// Steps: 8 broadcast b128 (own recurrence) + 32 fdot2 + tanh + b16 write.
// ---------------------------------------------------------------------------
__device__ __forceinline__ float layer_epoch(
    const __fp16* __restrict__ in0,   // [16][64] lower-layer slots (synced)
    __fp16* __restrict__ self0, int par,
    const h2_t* wB2, const h8_t* wX, float* __restrict__ xb,
    const float* bias4, int j)
{
    __fp16*       selfPar  = self0 + par * 1024;        // 16*64
    const __fp16* selfPrev = self0 + (par ^ 1) * 1024;
    const int mm = j & 15;
    const int q4 = j >> 4;

    // ---- x-part MFMA prologue (full 16 slots) ----
    F4H8 A0, A1;
    const __fp16* arow = in0 + mm * 64 + q4 * 8;
    A0.f = *(const float4*)arow;
    A1.f = *(const float4*)(arow + 32);

    f4_t xacc[4];
#pragma unroll
    for (int nt = 0; nt < 4; ++nt) {
#pragma unroll
        for (int i = 0; i < 4; ++i) xacc[nt][i] = 0.0f;
        xacc[nt] = __builtin_amdgcn_mfma_f32_16x16x32_f16(
            A0.h8, wX[nt * 2 + 0], xacc[nt], 0, 0, 0);
        xacc[nt] = __builtin_amdgcn_mfma_f32_16x16x32_f16(
            A1.h8, wX[nt * 2 + 1], xacc[nt], 0, 0, 0);
    }
#pragma unroll
    for (int nt = 0; nt < 4; ++nt)
#pragma unroll
        for (int i = 0; i < 4; ++i)
            xb[(q4 * 4 + i) * 64 + nt * 16 + mm] = xacc[nt][i] + bias4[nt];

    // read back own-lane xs (writes above are same-wave; LDS pipe is in-order)
    float xs[16];
#pragma unroll
    for (int s = 0; s < 16; ++s) xs[s] = xb[s * 64 + j];

    // ---- 16 recurrent steps ----
    float hN = 0.0f;
#pragma unroll
    for (int s = 0; s < 16; ++s) {
        const __fp16* rc = (s == 0) ? (selfPrev + 15 * 64) : (selfPar + (s - 1) * 64);
        F4H uh[8];
#pragma unroll
        for (int qq = 0; qq < 8; ++qq) uh[qq].f = *(const float4*)(rc + qq * 8);

        float a0 = 0.f, a1 = 0.f, a2 = 0.f, a3 = 0.f;
#pragma unroll
        for (int qq = 0; qq < 8; ++qq) {
            a0 = fdot2(wB2[qq * 4 + 0], uh[qq].h[0], a0);
            a1 = fdot2(wB2[qq * 4 + 1], uh[qq].h[1], a1);
            a2 = fdot2(wB2[qq * 4 + 2], uh[qq].h[2], a2);
            a3 = fdot2(wB2[qq * 4 + 3], uh[qq].h[3], a3);
        }
        hN = tanh_fast((a0 + a1) + (a2 + a3) + xs[s]);
        selfPar[s * 64 + j] = (__fp16)hN;
    }
    return hN;   // h of last step of this epoch
}

// ---------------------------------------------------------------------------
// Recurrence: block = batch element, 3 waves (wave g = layer g).
// Epochs of S=16 steps; ONE barrier per epoch. hb[layer][parity][slot][unit]:
// wave g writes slots of epoch e with parity e_g&1; consumer reads them
// next epoch (opposite parity) — WAR separated by exactly one barrier.
// xb2[g-1] is written+read by the SAME wave within an epoch (lgkm ordering).
// ---------------------------------------------------------------------------
__global__ __launch_bounds__(192, 1) void rnn_fused(
    const float* __restrict__ pre0,  // [128*512][64], layer-0 biases folded in
    const float* __restrict__ Whh0,
    const float* __restrict__ Wih1, const float* __restrict__ Whh1,
    const float* __restrict__ bih1, const float* __restrict__ bhh1,
    const float* __restrict__ Wih2, const float* __restrict__ Whh2,
    const float* __restrict__ bih2, const float* __restrict__ bhh2,
    const float* __restrict__ fcw, const float* __restrict__ fcb,
    float* __restrict__ out)
{
    const int tid = threadIdx.x;
    const int g   = tid >> 6;        // layer 0..2
    const int j   = tid & 63;        // output unit
    const int b   = blockIdx.x;

    __shared__ __align__(16) __fp16 hb[3][2][16][64];
    __shared__ __align__(16) float  xb2[2][16][64];

    // recurrent (Whh) rows packed f16, fdot2 path — all waves
    const float* WB = (g == 0) ? Whh0 : ((g == 1) ? Whh1 : Whh2);
    h2_t wB2[32];
#pragma unroll
    for (int i = 0; i < 32; ++i)
        wB2[i] = pack_h2(WB[j * 64 + 2 * i], WB[j * 64 + 2 * i + 1]);

    // Wih B-frags for the per-epoch x-MFMA (g1/g2; g0 loads dummy from Whh0)
    const float* WX = (g == 1) ? Wih1 : ((g == 2) ? Wih2 : Whh0);
    const int mm = j & 15, q4 = j >> 4;
    h8_t wX[8];
#pragma unroll
    for (int nt = 0; nt < 4; ++nt)
#pragma unroll
        for (int c = 0; c < 2; ++c) {
            const float* p = WX + (nt * 16 + mm) * 64 + c * 32 + q4 * 8;
            float4 r0 = *(const float4*)p;
            float4 r1 = *(const float4*)(p + 4);
            H8U u;
            u.h2[0] = pack_h2(r0.x, r0.y); u.h2[1] = pack_h2(r0.z, r0.w);
            u.h2[2] = pack_h2(r1.x, r1.y); u.h2[3] = pack_h2(r1.z, r1.w);
            wX[nt * 2 + c] = u.h8;
        }

    // per-lane scatter-column biases (col = nt*16 + mm), folded into xb
    float bias4[4];
#pragma unroll
    for (int nt = 0; nt < 4; ++nt) {
        const int col = nt * 16 + mm;
        bias4[nt] = (g == 1) ? (bih1[col] + bhh1[col])
                  : ((g == 2) ? (bih2[col] + bhh2[col]) : 0.0f);
    }

    // zero all of hb: 3*2*16*64 f16 = 3072 dwords / 192 thr = 16 each
#pragma unroll
    for (int i = 0; i < 16; ++i) ((unsigned int*)hb)[tid + 192 * i] = 0u;

    // pre0 double-buffered epoch prefetch (wave 0)
    const size_t pbase = (size_t)b * 32768;
    float pc[16], pn[16];
    if (g == 0) {
#pragma unroll
        for (int s = 0; s < 16; ++s) pc[s] = pre0[pbase + s * 64 + j];
    }
    __syncthreads();

    float hLast = 0.0f;

    for (int e = 0; e < 34; ++e) {
        if (g == 0) {
            if (e < 32) {
                if (e < 31) {
#pragma unroll
                    for (int s = 0; s < 16; ++s)
                        pn[s] = pre0[pbase + (size_t)(e + 1) * 1024 + s * 64 + j];
                }
                const int par = e & 1;
#pragma unroll
                for (int s = 0; s < 16; ++s) {
                    const __fp16* rc = (s == 0) ? hb[0][par ^ 1][15] : hb[0][par][s - 1];
                    float a0 = 0.f, a1 = 0.f, a2 = 0.f, a3 = 0.f;
#pragma unroll
                    for (int qq = 0; qq < 8; ++qq) {
                        F4H u; u.f = *(const float4*)&rc[qq * 8];
                        a0 = fdot2(wB2[qq * 4 + 0], u.h[0], a0);
                        a1 = fdot2(wB2[qq * 4 + 1], u.h[1], a1);
                        a2 = fdot2(wB2[qq * 4 + 2], u.h[2], a2);
                        a3 = fdot2(wB2[qq * 4 + 3], u.h[3], a3);
                    }
                    float hN = tanh_fast((a0 + a1) + (a2 + a3) + pc[s]);
                    hb[0][par][s][j] = (__fp16)hN;
                }
#pragma unroll
                for (int s = 0; s < 16; ++s) pc[s] = pn[s];
            }
        } else if (g == 1) {
            if (e >= 1 && e < 33) {
                const int par = (e - 1) & 1;
                layer_epoch(&hb[0][par][0][0], &hb[1][0][0][0], par,
                            wB2, wX, &xb2[0][0][0], bias4, j);
            }
        } else {
            if (e >= 2) {
                const int par = e & 1;   // == (e-2)&1
                float hN = layer_epoch(&hb[1][par][0][0], &hb[2][0][0][0], par,
                                       wB2, wX, &xb2[1][0][0], bias4, j);
                if (e == 33) hLast = hN;   // t = 511
            }
        }
        __syncthreads();
    }

    // FC epilogue on wave 2
    if (g == 2) {
        float v = hLast * fcw[j];
#pragma unroll
        for (int m = 1; m < 64; m <<= 1) v += __shfl_xor(v, m, 64);
        if (j == 0) out[b] = v + fcb[0];
    }
}

extern "C" void kernel_launch(void* const* d_in, const int* in_sizes, int n_in,
                              void* d_out, int out_size, void* d_ws, size_t ws_size,
                              hipStream_t stream) {
    const float* x    = (const float*)d_in[0];
    const float* Wih0 = (const float*)d_in[2];
    const float* Whh0 = (const float*)d_in[3];
    const float* bih0 = (const float*)d_in[4];
    const float* bhh0 = (const float*)d_in[5];
    const float* Wih1 = (const float*)d_in[6];
    const float* Whh1 = (const float*)d_in[7];
    const float* bih1 = (const float*)d_in[8];
    const float* bhh1 = (const float*)d_in[9];
    const float* Wih2 = (const float*)d_in[10];
    const float* Whh2 = (const float*)d_in[11];
    const float* bih2 = (const float*)d_in[12];
    const float* bhh2 = (const float*)d_in[13];
    const float* fcw  = (const float*)d_in[14];
    const float* fcb  = (const float*)d_in[15];
    float* out  = (float*)d_out;
    float* pre0 = (float*)d_ws;                      // 16.78 MB fp32
    h8_t* wpack = (h8_t*)((char*)d_ws + (size_t)65536 * 64 * 4);  // 96 KB

    pack_wih<<<24, 256, 0, stream>>>(Wih0, wpack);
    gemm_pre0<<<1024, 256, 0, stream>>>(x, wpack, bih0, bhh0, pre0);
    rnn_fused<<<128, 192, 0, stream>>>(pre0, Whh0, Wih1, Whh1, bih1, bhh1,
                                       Wih2, Whh2, bih2, bhh2, fcw, fcb, out);
}